// Round 1
// baseline (8811.613 us; speedup 1.0000x reference)
//
#include <hip/hip_runtime.h>
#include <hip/hip_bf16.h>

#define DEV __device__ __forceinline__

namespace {

constexpr int Bn  = 4, SEQ = 1024, NV = 32, PL = 16, D = 512, H = 8, DFF = 2048;
constexpr int P   = SEQ / PL;    // 64 patches
constexpr int L   = P * NV;      // 2048 tokens per batch
constexpr int M   = Bn * L;      // 8192 total token rows
constexpr int DH  = D / H;       // 64
constexpr int WIN = 4;

// flag-dispatched float load: bf=1 -> bf16, bf=0 -> fp32
DEV float ldf(const void* p, int idx, int bf) {
  if (bf) return __bfloat162float(((const __hip_bfloat16*)p)[idx]);
  return ((const float*)p)[idx];
}

// ---------------------------------------------------------------------------
// k_setup: detect input float dtype (via gf == ones), detect mask storage
// format, canonicalize mask to int32, count masked tokens, zero accumulators.
// ---------------------------------------------------------------------------
__global__ void k_setup(const void* gf, const void* mask_raw, int* mask_i,
                        int* flags, float* scal) {
  __shared__ int s_gt1, s_oth, s_cnt;
  int tid = threadIdx.x;
  if (tid == 0) { s_gt1 = 0; s_oth = 0; s_cnt = 0; }
  __syncthreads();
  const unsigned* mw = (const unsigned*)mask_raw;
  int gt1 = 0, oth = 0;
  // 2048 words = 8KB: safe to read under byte(8KB)/int32(32KB)/f32(32KB) views
  for (int i = tid; i < 2048; i += 256) {
    unsigned w = mw[i];
    if (w > 1u) { gt1 = 1; if (w != 0x3F800000u) oth = 1; }
  }
  if (gt1) atomicOr(&s_gt1, 1);
  if (oth) atomicOr(&s_oth, 1);
  __syncthreads();
  int fmt = (!s_gt1) ? 0 : (!s_oth ? 1 : 2);  // 0=int32, 1=f32, 2=bytes
  int cnt = 0;
  for (int i = tid; i < Bn * P * NV; i += 256) {
    int m;
    if (fmt == 0)      m = ((const int*)mask_raw)[i] != 0;
    else if (fmt == 1) m = ((const float*)mask_raw)[i] != 0.0f;
    else               m = ((const unsigned char*)mask_raw)[i] != 0;
    mask_i[i] = m; cnt += m;
  }
  atomicAdd(&s_cnt, cnt);
  __syncthreads();
  if (tid == 0) {
    unsigned w = *(const unsigned*)gf;       // gf[0] == 1.0
    flags[0] = ((w & 0xFFFFu) == 0x3F80u) ? 1 : 0;  // bf16 if low half 0x3F80
    flags[1] = s_cnt;                         // number of masked tokens
    scal[0] = 0.f;                            // loss accumulator
  }
}

// ---------------------------------------------------------------------------
// k_stats: per (b, v) mean / stdev over the SEQ axis. One wave per (b,v).
// ---------------------------------------------------------------------------
__global__ void k_stats(const void* x, const int* flags, float* means,
                        float* stdev) {
  int bv = blockIdx.x; int b = bv >> 5, v = bv & 31;
  int bf = flags[0];
  int lane = threadIdx.x;
  float s = 0.f, s2 = 0.f;
  for (int t = lane; t < SEQ; t += 64) {
    float val = ldf(x, b * SEQ * NV + t * NV + v, bf);
    s += val; s2 += val * val;
  }
  for (int off = 32; off; off >>= 1) {
    s  += __shfl_down(s, off);
    s2 += __shfl_down(s2, off);
  }
  if (lane == 0) {
    float m = s / (float)SEQ;
    float var = s2 / (float)SEQ - m * m;
    means[bv] = m;
    stdev[bv] = sqrtf(var + 1e-5f);
  }
}

// ---------------------------------------------------------------------------
// k_embed: patchify + normalize, write patches buffer, embed (patch @ W_embed
// + b_embed), zero masked tokens. One block (128 thr) per token.
// ---------------------------------------------------------------------------
__global__ void k_embed(const void* x, const void* We, const void* be,
                        const int* flags, const int* mask_i,
                        const float* means, const float* stdev,
                        float* patches, float* tok) {
  int idx = blockIdx.x;                 // = b*2048 + p*32 + v = token row
  int b = idx >> 11, pv = idx & 2047, p = pv >> 5, v = pv & 31;
  int bf = flags[0];
  __shared__ float pvs[PL];
  int tid = threadIdx.x;
  float m = means[b * NV + v], sd = stdev[b * NV + v];
  if (tid < PL) {
    float val = (ldf(x, b * SEQ * NV + (p * PL + tid) * NV + v, bf) - m) / sd;
    pvs[tid] = val;
    patches[idx * PL + tid] = val;
  }
  __syncthreads();
  int masked = mask_i[idx];
  for (int d = tid; d < D; d += 128) {
    float acc = ldf(be, d, bf);
    for (int t = 0; t < PL; t++) acc += pvs[t] * ldf(We, t * D + d, bf);
    tok[idx * D + d] = masked ? 0.f : acc;
  }
}

// ---------------------------------------------------------------------------
// k_gemm: C[M x N] = act(A @ W + bias [+ resid]).  A fp32 (ws), W/bias flag-
// typed input with element offsets. 64x64 tile, 256 thr, 4x4 micro-tile.
// act: 0 = none, 1 = exact GELU.
// ---------------------------------------------------------------------------
__global__ void k_gemm(const float* A, const void* W, const void* bias,
                       const float* resid, float* C, int Mm, int Nn, int Kk,
                       int act, int woff, int boff, const int* flags) {
  int bf = flags[0];
  __shared__ float As[16][65];
  __shared__ float Ws[16][65];
  int tid = threadIdx.x;
  int bm = blockIdx.y * 64, bn = blockIdx.x * 64;
  int tx = tid & 15, ty = tid >> 4;
  float acc[4][4] = {};
  for (int k0 = 0; k0 < Kk; k0 += 16) {
    for (int e = tid; e < 1024; e += 256) {
      int m = e >> 4, k = e & 15;
      As[k][m] = A[(bm + m) * Kk + k0 + k];
    }
    for (int e = tid; e < 1024; e += 256) {
      int k = e >> 6, n = e & 63;
      Ws[k][n] = ldf(W, woff + (k0 + k) * Nn + bn + n, bf);
    }
    __syncthreads();
    for (int k = 0; k < 16; k++) {
      float av[4], wv[4];
      for (int i = 0; i < 4; i++) av[i] = As[k][ty * 4 + i];
      for (int j = 0; j < 4; j++) wv[j] = Ws[k][tx * 4 + j];
      for (int i = 0; i < 4; i++)
        for (int j = 0; j < 4; j++) acc[i][j] += av[i] * wv[j];
    }
    __syncthreads();
  }
  for (int i = 0; i < 4; i++) {
    int m = bm + ty * 4 + i;
    for (int j = 0; j < 4; j++) {
      int n = bn + tx * 4 + j;
      float c = acc[i][j] + ldf(bias, boff + n, bf);
      if (resid) c += resid[m * Nn + n];
      if (act == 1) c = 0.5f * c * (1.f + erff(c * 0.70710678118f));
      C[m * Nn + n] = c;
    }
  }
}

// ---------------------------------------------------------------------------
// k_attn: banded attention. Block per (p, h, b). Scores strip (<=32x288) in
// LDS, row softmax, O = A @ V. q/k/v/o stored as [B, L, D] fp32.
// ---------------------------------------------------------------------------
__global__ void k_attn(const float* q, const float* k, const float* v,
                       float* o) {
  int p = blockIdx.x, h = blockIdx.y, b = blockIdx.z;
  __shared__ float Q[32][DH];
  __shared__ float T[32][DH];
  __shared__ float S[32][(2 * WIN + 1) * 32];   // 32 x 288
  int tid = threadIdx.x;
  int p0 = (p > WIN) ? (p - WIN) : 0;
  int p1 = (p + WIN < P) ? (p + WIN) : (P - 1);
  int nk = (p1 - p0 + 1) * 32;
  int base = b * L;
  for (int e = tid; e < 32 * DH; e += 256) {
    int i = e >> 6, d = e & 63;
    Q[i][d] = q[(base + p * 32 + i) * D + h * DH + d];
  }
  __syncthreads();
  int i = tid >> 3, j0 = (tid & 7) * 4;
  for (int kp = p0; kp <= p1; kp++) {
    int co = (kp - p0) * 32;
    for (int e = tid; e < 32 * DH; e += 256) {
      int j = e >> 6, d = e & 63;
      T[j][d] = k[(base + kp * 32 + j) * D + h * DH + d];
    }
    __syncthreads();
    for (int jj = 0; jj < 4; jj++) {
      float s = 0.f;
      for (int d = 0; d < DH; d++) s += Q[i][d] * T[j0 + jj][d];
      S[i][co + j0 + jj] = s;
    }
    __syncthreads();
  }
  if (tid < 32) {
    float mx = -1e30f;
    for (int j = 0; j < nk; j++) {
      float t = S[tid][j] * 0.125f;   // SCALE = 1/sqrt(64)
      S[tid][j] = t;
      if (t > mx) mx = t;
    }
    float sum = 0.f;
    for (int j = 0; j < nk; j++) {
      float e = expf(S[tid][j] - mx);
      S[tid][j] = e; sum += e;
    }
    float inv = 1.f / sum;
    for (int j = 0; j < nk; j++) S[tid][j] *= inv;
  }
  __syncthreads();
  float acc[8] = {};
  int d0 = (tid & 7) * 8;
  for (int kp = p0; kp <= p1; kp++) {
    int co = (kp - p0) * 32;
    for (int e = tid; e < 32 * DH; e += 256) {
      int j = e >> 6, d = e & 63;
      T[j][d] = v[(base + kp * 32 + j) * D + h * DH + d];
    }
    __syncthreads();
    for (int j = 0; j < 32; j++) {
      float a = S[i][co + j];
      for (int dd = 0; dd < 8; dd++) acc[dd] += a * T[j][d0 + dd];
    }
    __syncthreads();
  }
  for (int dd = 0; dd < 8; dd++)
    o[(base + p * 32 + i) * D + h * DH + d0 + dd] = acc[dd];
}

// ---------------------------------------------------------------------------
// k_ln: layernorm over D=512 per token. One wave per row.
// ---------------------------------------------------------------------------
__global__ void k_ln(const float* x, const void* g, const void* bta,
                     float* out, const int* flags, int goff) {
  int row = blockIdx.x;
  int bf = flags[0];
  int lane = threadIdx.x;
  float s = 0.f, s2 = 0.f, vals[8];
  for (int i = 0; i < 8; i++) {
    float t = x[row * D + lane + i * 64];
    vals[i] = t; s += t; s2 += t * t;
  }
  for (int off = 32; off; off >>= 1) {
    s  += __shfl_down(s, off);
    s2 += __shfl_down(s2, off);
  }
  s = __shfl(s, 0); s2 = __shfl(s2, 0);
  float m = s / (float)D, var = s2 / (float)D - m * m;
  float inv = rsqrtf(var + 1e-5f);
  for (int i = 0; i < 8; i++) {
    int c = lane + i * 64;
    out[row * D + c] = (vals[i] - m) * inv * ldf(g, goff + c, bf) +
                       ldf(bta, goff + c, bf);
  }
}

// ---------------------------------------------------------------------------
// k_loss: recon head + masked MSE. Block per (b,p): 32 tokens x 16 outputs.
// diff = sc * (enc@Wp + bp - patches);  loss += sc^2 * diff^2 over masked.
// ---------------------------------------------------------------------------
__global__ void k_loss(const float* tokf, const void* Wp, const void* bp,
                       const float* patches, const float* stdev,
                       const int* mask_i, const int* flags, float* scal) {
  int bpI = blockIdx.x; int b = bpI >> 6, p = bpI & 63;
  int bf = flags[0];
  int tid = threadIdx.x;
  float local = 0.f;
  for (int e = tid * 4; e < tid * 4 + 4; e++) {   // e in [0,512): v=e>>4, t=e&15
    int v = e >> 4, t = e & 15;
    int tokidx = b * L + p * 32 + v;              // == mask index == patch row
    if (mask_i[tokidx]) {
      float r = ldf(bp, t, bf);
      for (int d = 0; d < D; d++)
        r += tokf[tokidx * D + d] * ldf(Wp, d * PL + t, bf);
      float diff = r - patches[tokidx * PL + t];
      float sc = stdev[b * NV + v];
      local += sc * sc * diff * diff;
    }
  }
  __shared__ float red[128];
  red[tid] = local;
  __syncthreads();
  for (int s = 64; s; s >>= 1) {
    if (tid < s) red[tid] += red[tid + s];
    __syncthreads();
  }
  if (tid == 0) atomicAdd(&scal[0], red[0]);
}

// ---------------------------------------------------------------------------
// k_final: divide, emit dual-format scalar: word = (bf16(loss)<<16)|bf16(loss)
// valid under both bf16 (low half) and fp32 (full word) readers.
// ---------------------------------------------------------------------------
__global__ void k_final(const float* scal, const int* flags, unsigned* out) {
  float denom = (float)flags[1] * (float)PL;
  if (denom == 0.f) denom = 1.f;
  float loss = scal[0] / denom;
  unsigned fb = __float_as_uint(loss);
  unsigned u = (fb + 0x7FFFu + ((fb >> 16) & 1u)) >> 16;  // RNE bf16
  out[0] = (u << 16) | u;
}

}  // namespace

extern "C" void kernel_launch(void* const* d_in, const int* in_sizes, int n_in,
                              void* d_out, int out_size, void* d_ws,
                              size_t ws_size, hipStream_t stream) {
  const void* x_enc = d_in[0];
  const void* maskp = d_in[1];
  const void* We = d_in[2];  const void* be_ = d_in[3];
  const void* Wq = d_in[4];  const void* bq = d_in[5];
  const void* Wk = d_in[6];  const void* bk = d_in[7];
  const void* Wv = d_in[8];  const void* bv = d_in[9];
  const void* Wo = d_in[10]; const void* bo_ = d_in[11];
  const void* W1 = d_in[12]; const void* b1 = d_in[13];
  const void* W2 = d_in[14]; const void* b2 = d_in[15];
  const void* g1 = d_in[16]; const void* be1 = d_in[17];
  const void* g2 = d_in[18]; const void* be2 = d_in[19];
  const void* gf = d_in[20]; const void* bff = d_in[21];
  const void* Wp = d_in[22]; const void* bp = d_in[23];

  // workspace layout (bytes). hidden (64MB) aliases the dead q/k/v/o region.
  char* w = (char*)d_ws;
  int*   mask_i  = (int*)w;                          // 32 KB
  int*   flags   = (int*)(w + (32u << 10));
  float* scal    = (float*)(w + (33u << 10));
  float* means   = (float*)(w + (34u << 10));
  float* stdev   = (float*)(w + (35u << 10));
  float* patches = (float*)(w + (64u << 10));        // 512 KB
  float* tok     = (float*)(w + (1u  << 20));        // 16 MB
  float* tmp     = (float*)(w + (18u << 20));        // 16 MB
  float* qb      = (float*)(w + (35u << 20));        // 16 MB
  float* kb      = (float*)(w + (51u << 20));        // 16 MB
  float* vb      = (float*)(w + (67u << 20));        // 16 MB
  float* ob      = (float*)(w + (83u << 20));        // 16 MB (ends at 99 MB)
  float* hidden  = qb;                               // 64 MB alias

  k_setup<<<1, 256, 0, stream>>>(gf, maskp, mask_i, flags, scal);
  k_stats<<<Bn * NV, 64, 0, stream>>>(x_enc, flags, means, stdev);
  k_embed<<<Bn * P * NV, 128, 0, stream>>>(x_enc, We, be_, flags, mask_i,
                                           means, stdev, patches, tok);
  for (int l = 0; l < 4; l++) {
    int wOff = l * D * D, bOff = l * D;
    dim3 gD(D / 64, M / 64), gF(DFF / 64, M / 64);
    k_gemm<<<gD, 256, 0, stream>>>(tok, Wq, bq, nullptr, qb, M, D, D, 0,
                                   wOff, bOff, flags);
    k_gemm<<<gD, 256, 0, stream>>>(tok, Wk, bk, nullptr, kb, M, D, D, 0,
                                   wOff, bOff, flags);
    k_gemm<<<gD, 256, 0, stream>>>(tok, Wv, bv, nullptr, vb, M, D, D, 0,
                                   wOff, bOff, flags);
    k_attn<<<dim3(P, H, Bn), 256, 0, stream>>>(qb, kb, vb, ob);
    k_gemm<<<gD, 256, 0, stream>>>(ob, Wo, bo_, tok, tmp, M, D, D, 0,
                                   wOff, bOff, flags);
    k_ln<<<M, 64, 0, stream>>>(tmp, g1, be1, tok, flags, l * D);
    k_gemm<<<gF, 256, 0, stream>>>(tok, W1, b1, nullptr, hidden, M, DFF, D, 1,
                                   l * D * DFF, l * DFF, flags);
    k_gemm<<<gD, 256, 0, stream>>>(hidden, W2, b2, tok, tmp, M, D, DFF, 0,
                                   l * DFF * D, l * D, flags);
    k_ln<<<M, 64, 0, stream>>>(tmp, g2, be2, tok, flags, l * D);
  }
  k_ln<<<M, 64, 0, stream>>>(tok, gf, bff, tmp, flags, 0);
  k_loss<<<Bn * P, 128, 0, stream>>>(tmp, Wp, bp, patches, stdev, mask_i,
                                     flags, scal);
  k_final<<<1, 1, 0, stream>>>(scal, flags, (unsigned*)d_out);
}

// Round 2
// 1312.239 us; speedup vs baseline: 6.7149x; 6.7149x over previous
//
#include <hip/hip_runtime.h>
#include <hip/hip_bf16.h>

#define DEV __device__ __forceinline__

namespace {

constexpr int Bn  = 4, SEQ = 1024, NV = 32, PL = 16, D = 512, H = 8, DFF = 2048;
constexpr int P   = SEQ / PL;    // 64 patches
constexpr int L   = P * NV;      // 2048 tokens per batch
constexpr int M   = Bn * L;      // 8192 total token rows
constexpr int WIN = 4;

using short8  = __attribute__((ext_vector_type(8))) short;
using ushort8 = __attribute__((ext_vector_type(8))) unsigned short;
using float4v = __attribute__((ext_vector_type(4))) float;

DEV float b2f(unsigned short u) { return __uint_as_float(((unsigned)u) << 16); }
DEV unsigned short f2b(float f) {
  unsigned fb = __float_as_uint(f);
  return (unsigned short)((fb + 0x7FFFu + ((fb >> 16) & 1u)) >> 16);
}
// flag-dispatched float load from an input tensor: bf=1 -> bf16, 0 -> fp32
DEV float ldf(const void* p, int idx, int bf) {
  if (bf) return b2f(((const unsigned short*)p)[idx]);
  return ((const float*)p)[idx];
}
// async global->LDS 16B: lds dest = wave-uniform base + lane*16
DEV void gll16(const void* gp, void* lp) {
  __builtin_amdgcn_global_load_lds(
      (const __attribute__((address_space(1))) void*)gp,
      (__attribute__((address_space(3))) void*)lp, 16, 0, 0);
}

// ---------------------------------------------------------------------------
// k_setup: detect float dtype + mask format, canonicalize mask, count masked.
// ---------------------------------------------------------------------------
__global__ void k_setup(const void* gf, const void* mask_raw, int* mask_i,
                        int* flags, float* scal) {
  __shared__ int s_gt1, s_oth, s_cnt;
  int tid = threadIdx.x;
  if (tid == 0) { s_gt1 = 0; s_oth = 0; s_cnt = 0; }
  __syncthreads();
  const unsigned* mw = (const unsigned*)mask_raw;
  int gt1 = 0, oth = 0;
  for (int i = tid; i < 2048; i += 256) {
    unsigned w = mw[i];
    if (w > 1u) { gt1 = 1; if (w != 0x3F800000u) oth = 1; }
  }
  if (gt1) atomicOr(&s_gt1, 1);
  if (oth) atomicOr(&s_oth, 1);
  __syncthreads();
  int fmt = (!s_gt1) ? 0 : (!s_oth ? 1 : 2);  // 0=int32, 1=f32, 2=bytes
  int cnt = 0;
  for (int i = tid; i < Bn * P * NV; i += 256) {
    int m;
    if (fmt == 0)      m = ((const int*)mask_raw)[i] != 0;
    else if (fmt == 1) m = ((const float*)mask_raw)[i] != 0.0f;
    else               m = ((const unsigned char*)mask_raw)[i] != 0;
    mask_i[i] = m; cnt += m;
  }
  atomicAdd(&s_cnt, cnt);
  __syncthreads();
  if (tid == 0) {
    unsigned w = *(const unsigned*)gf;
    flags[0] = ((w & 0xFFFFu) == 0x3F80u) ? 1 : 0;
    flags[1] = s_cnt;
    scal[0] = 0.f;
  }
}

// ---------------------------------------------------------------------------
// k_stats: per (b,v) mean/stdev over time. One wave per (b,v).
// ---------------------------------------------------------------------------
__global__ void k_stats(const void* x, const int* flags, float* means,
                        float* stdev) {
  int bv = blockIdx.x; int b = bv >> 5, v = bv & 31;
  int bf = flags[0];
  int lane = threadIdx.x;
  float s = 0.f, s2 = 0.f;
  for (int t = lane; t < SEQ; t += 64) {
    float val = ldf(x, b * SEQ * NV + t * NV + v, bf);
    s += val; s2 += val * val;
  }
  for (int off = 32; off; off >>= 1) {
    s  += __shfl_down(s, off);
    s2 += __shfl_down(s2, off);
  }
  if (lane == 0) {
    float m = s / (float)SEQ;
    means[bv] = m;
    stdev[bv] = sqrtf(s2 / (float)SEQ - m * m + 1e-5f);
  }
}

// ---------------------------------------------------------------------------
// k_bias: gather all GEMM biases into fp32 ws array.
// layout (floats): qkvb l*1536 | 6144+obias l*512 | 8192+b1 l*2048 | 16384+b2 l*512
// ---------------------------------------------------------------------------
__global__ void k_bias(const void* bq, const void* bk, const void* bv,
                       const void* bo, const void* b1, const void* b2,
                       const int* flags, float* biasf) {
  int i = blockIdx.x * 256 + threadIdx.x;
  if (i >= 4 * 4608) return;
  int bf = flags[0];
  int l = i / 4608, r = i % 4608;
  if (r < 1536) {
    float v = (r < 512) ? ldf(bq, l * 512 + r, bf)
            : (r < 1024) ? ldf(bk, l * 512 + r - 512, bf)
                         : ldf(bv, l * 512 + r - 1024, bf);
    biasf[l * 1536 + r] = v;
  } else if (r < 2048) {
    biasf[6144 + l * 512 + (r - 1536)] = ldf(bo, l * 512 + r - 1536, bf);
  } else if (r < 4096) {
    biasf[8192 + l * 2048 + (r - 2048)] = ldf(b1, l * 2048 + r - 2048, bf);
  } else {
    biasf[16384 + l * 512 + (r - 4096)] = ldf(b2, l * 512 + r - 4096, bf);
  }
}

// ---------------------------------------------------------------------------
// k_transpose: dst[l][n][k] (bf16) = src[l][k][n].  32x32 LDS tile.
// ---------------------------------------------------------------------------
__global__ void k_transpose(const void* src, unsigned short* dst, int Kd,
                            int Nd, int srcLS, int dstLS, int dstOff,
                            const int* flags) {
  int bf = flags[0];
  int tx = threadIdx.x & 31, ty = threadIdx.x >> 5;
  int k0 = blockIdx.y * 32, n0 = blockIdx.x * 32, l = blockIdx.z;
  __shared__ float t[32][33];
  for (int rr = ty; rr < 32; rr += 8)
    t[rr][tx] = ldf(src, l * srcLS + (k0 + rr) * Nd + n0 + tx, bf);
  __syncthreads();
  for (int rr = ty; rr < 32; rr += 8)
    dst[(size_t)l * dstLS + dstOff + (size_t)(n0 + rr) * Kd + k0 + tx] =
        f2b(t[tx][rr]);
}

// ---------------------------------------------------------------------------
// k_embed: patchify + instance-normalize, write patches (fp32) and embedded
// tokens (bf16), zeroing masked tokens. One block (128 thr) per token.
// ---------------------------------------------------------------------------
__global__ void k_embed(const void* x, const void* We, const void* be,
                        const int* flags, const int* mask_i,
                        const float* means, const float* stdev,
                        float* patches, unsigned short* tok) {
  int idx = blockIdx.x;
  int b = idx >> 11, pv = idx & 2047, p = pv >> 5, v = pv & 31;
  int bf = flags[0];
  __shared__ float pvs[PL];
  int tid = threadIdx.x;
  float m = means[b * NV + v], sd = stdev[b * NV + v];
  if (tid < PL) {
    float val = (ldf(x, b * SEQ * NV + (p * PL + tid) * NV + v, bf) - m) / sd;
    pvs[tid] = val;
    patches[idx * PL + tid] = val;
  }
  __syncthreads();
  int masked = mask_i[idx];
  for (int d = tid; d < D; d += 128) {
    float acc = ldf(be, d, bf);
    for (int t = 0; t < PL; t++) acc += pvs[t] * ldf(We, t * D + d, bf);
    tok[(size_t)idx * D + d] = masked ? f2b(0.f) : f2b(acc);
  }
}

// ---------------------------------------------------------------------------
// k_gemm<BM,WN>: C[bm..][bn..] = act(A @ W^T' + bias [+resid]) in bf16.
// A: [M][Kk] bf16 row-major; W: pre-transposed [Nn][Kk] bf16 row-major.
// 256 thr = 4 waves; tile BM x 128; wave computes 64 x WN via 16x16x32 MFMA.
// ---------------------------------------------------------------------------
template <int BM, int WN>
__global__ __launch_bounds__(256) void k_gemm(
    const unsigned short* __restrict__ A, const unsigned short* __restrict__ W,
    const float* __restrict__ bias, const unsigned short* __restrict__ resid,
    unsigned short* __restrict__ C, int Nn, int Kk, int act) {
  constexpr int FI = 4, FJ = WN / 16, NWN = 128 / WN;
  __shared__ __align__(16) char As[BM * 64];    // BM x 32 bf16
  __shared__ __align__(16) char Bs[128 * 64];   // 128 x 32 bf16
  int tid = threadIdx.x, lane = tid & 63, w = tid >> 6;
  int lane15 = lane & 15, q = lane >> 4;
  int wm = w / NWN, wn = w % NWN;
  int bm = blockIdx.y * BM, bn = blockIdx.x * 128;
  float4v acc[FI][FJ];
  for (int i = 0; i < FI; i++)
    for (int j = 0; j < FJ; j++) acc[i][j] = 0;
  for (int k0 = 0; k0 < Kk; k0 += 32) {
    if (k0) __syncthreads();
    for (int r = 0; r < BM / 64; r++) {
      int cc = r * 256 + w * 64 + lane;
      int row = cc >> 2, kc = cc & 3;
      gll16(A + (size_t)(bm + row) * Kk + k0 + kc * 8,
            As + (r * 256 + w * 64) * 16);
    }
    for (int r = 0; r < 2; r++) {
      int cc = r * 256 + w * 64 + lane;
      int row = cc >> 2, kc = cc & 3;
      gll16(W + (size_t)(bn + row) * Kk + k0 + kc * 8,
            Bs + (r * 256 + w * 64) * 16);
    }
    __syncthreads();
    short8 a[FI], b[FJ];
    for (int i = 0; i < FI; i++)
      a[i] = *(const short8*)(As + (wm * 64 + i * 16 + lane15) * 64 + q * 16);
    for (int j = 0; j < FJ; j++)
      b[j] = *(const short8*)(Bs + (wn * WN + j * 16 + lane15) * 64 + q * 16);
    for (int i = 0; i < FI; i++)
      for (int j = 0; j < FJ; j++)
        acc[i][j] = __builtin_amdgcn_mfma_f32_16x16x32_bf16(a[i], b[j],
                                                            acc[i][j], 0, 0, 0);
  }
  for (int i = 0; i < FI; i++) {
    int row = bm + wm * 64 + i * 16 + q * 4;
    for (int j = 0; j < FJ; j++) {
      int col = bn + wn * WN + j * 16 + lane15;
      float bv = bias[col];
      for (int r = 0; r < 4; r++) {
        float cv = acc[i][j][r] + bv;
        size_t off = (size_t)(row + r) * Nn + col;
        if (resid) cv += b2f(resid[off]);
        if (act) cv = 0.5f * cv * (1.f + erff(cv * 0.70710678f));
        C[off] = f2b(cv);
      }
    }
  }
}

// ---------------------------------------------------------------------------
// k_attn: banded MFMA attention. Block per (p,h,b), 4 waves.
// qkv: [M][1536] bf16 (q|k|v). o: [M][512] bf16.
// LDS plan (63744 B static):
//   [0,4608)      Qs 32x72 bf16      (phase A)   -> Ps 32x296 bf16 (phase B/C)
//   [4608,25344)  Ks 144x72 bf16     (phase A, two window halves)
//   [25344,63744) Ss 32x300 fp32     (scores)    -> Vt 64x296 bf16 (phase C)
// ---------------------------------------------------------------------------
__global__ __launch_bounds__(256) void k_attn(const unsigned short* __restrict__ qkv,
                                              unsigned short* __restrict__ o) {
  constexpr int QS = 0, KS = 4608, PS = 0, SS = 25344, VT = 25344;
  __shared__ __align__(16) char sm[63744];
  int p = blockIdx.x, h = blockIdx.y, b = blockIdx.z;
  int tid = threadIdx.x, lane = tid & 63, w = tid >> 6;
  int lane15 = lane & 15, q = lane >> 4;
  int p0 = max(0, p - WIN), p1 = min(P - 1, p + WIN);
  int nk = (p1 - p0 + 1) * 32;              // multiple of 32, in [160,288]
  size_t base = (size_t)b * L;
  size_t qrow0 = (base + p * 32) * 1536 + (size_t)h * 64;
  size_t krow0 = (base + p0 * 32) * 1536 + 512 + (size_t)h * 64;
  size_t vrow0 = (base + p0 * 32) * 1536 + 1024 + (size_t)h * 64;
  int mtile = w & 1;
  short8 aq[2];
  // ---- phase A: S = Q K^T (two halves of the 288-key window) ----
  for (int half = 0; half < 2; half++) {
    if (half) __syncthreads();
    for (int e = tid; e < 144 * 8; e += 256) {
      int jr = e >> 3, sub = e & 7;
      if (half * 144 + jr < nk) {
        ushort8 t = *(const ushort8*)(qkv + krow0 +
                                      (size_t)(half * 144 + jr) * 1536 + sub * 8);
        *(ushort8*)(sm + KS + jr * 144 + sub * 16) = t;
      }
    }
    if (half == 0) {
      int rr = tid >> 3, sub = tid & 7;
      ushort8 t = *(const ushort8*)(qkv + qrow0 + (size_t)rr * 1536 + sub * 8);
      *(ushort8*)(sm + QS + rr * 144 + sub * 16) = t;
    }
    __syncthreads();
    if (half == 0) {
      aq[0] = *(const short8*)(sm + QS + (mtile * 16 + lane15) * 144 + q * 16);
      aq[1] = *(const short8*)(sm + QS + (mtile * 16 + lane15) * 144 + 64 + q * 16);
    }
    for (int nt = (w >> 1); nt < 9; nt += 2) {
      if (half * 144 + nt * 16 >= nk) break;
      short8 b0 = *(const short8*)(sm + KS + (nt * 16 + lane15) * 144 + q * 16);
      short8 b1 = *(const short8*)(sm + KS + (nt * 16 + lane15) * 144 + 64 + q * 16);
      float4v s4 = 0;
      s4 = __builtin_amdgcn_mfma_f32_16x16x32_bf16(aq[0], b0, s4, 0, 0, 0);
      s4 = __builtin_amdgcn_mfma_f32_16x16x32_bf16(aq[1], b1, s4, 0, 0, 0);
      float* ss = (float*)(sm + SS);
      for (int r = 0; r < 4; r++)
        ss[(mtile * 16 + q * 4 + r) * 300 + half * 144 + nt * 16 + lane15] = s4[r];
    }
  }
  __syncthreads();
  // ---- phase B: softmax (8 threads per row), write P bf16 into PS ----
  {
    float* ss = (float*)(sm + SS);
    unsigned short* ps = (unsigned short*)(sm + PS);
    int row = tid >> 3, c = tid & 7;
    float mx = -3e38f;
    for (int j = c; j < nk; j += 8) mx = fmaxf(mx, ss[row * 300 + j] * 0.125f);
    for (int off = 1; off < 8; off <<= 1) mx = fmaxf(mx, __shfl_xor(mx, off));
    float sum = 0.f;
    for (int j = c; j < nk; j += 8) {
      float e = __expf(ss[row * 300 + j] * 0.125f - mx);
      ss[row * 300 + j] = e; sum += e;
    }
    for (int off = 1; off < 8; off <<= 1) sum += __shfl_xor(sum, off);
    float inv = 1.f / sum;
    for (int j = c; j < nk; j += 8)
      ps[row * 296 + j] = f2b(ss[row * 300 + j] * inv);
  }
  __syncthreads();
  // ---- phase C: load V^T over Ss, O = P V ----
  for (int e = tid; e < nk * 64; e += 256) {
    int kl = e >> 6, n = e & 63;
    ((unsigned short*)(sm + VT))[n * 296 + kl] =
        qkv[vrow0 + (size_t)kl * 1536 + n];
  }
  __syncthreads();
  int ntb = (w >> 1) * 2;
  float4v oa[2]; oa[0] = 0; oa[1] = 0;
  for (int kt = 0; kt < (nk >> 5); kt++) {
    short8 ap = *(const short8*)(sm + PS + (mtile * 16 + lane15) * 592 +
                                 kt * 64 + q * 16);
    for (int jj = 0; jj < 2; jj++) {
      short8 bv = *(const short8*)(sm + VT + ((ntb + jj) * 16 + lane15) * 592 +
                                   kt * 64 + q * 16);
      oa[jj] = __builtin_amdgcn_mfma_f32_16x16x32_bf16(ap, bv, oa[jj], 0, 0, 0);
    }
  }
  for (int jj = 0; jj < 2; jj++)
    for (int r = 0; r < 4; r++)
      o[(base + p * 32 + mtile * 16 + q * 4 + r) * 512 + h * 64 +
        (ntb + jj) * 16 + lane15] = f2b(oa[jj][r]);
}

// ---------------------------------------------------------------------------
// k_ln: layernorm over D=512 per token, bf16 in/out. 4 rows per block.
// ---------------------------------------------------------------------------
__global__ void k_ln(const unsigned short* __restrict__ x, const void* g,
                     const void* bta, unsigned short* __restrict__ out,
                     const int* flags, int goff) {
  int bf = flags[0];
  int row = blockIdx.x * 4 + (threadIdx.x >> 6);
  int lane = threadIdx.x & 63;
  ushort8 u = *(const ushort8*)(x + (size_t)row * D + lane * 8);
  float v[8]; float s = 0.f, s2 = 0.f;
  for (int t = 0; t < 8; t++) {
    v[t] = b2f(u[t]); s += v[t]; s2 += v[t] * v[t];
  }
  for (int off = 32; off; off >>= 1) {
    s += __shfl_xor(s, off); s2 += __shfl_xor(s2, off);
  }
  float m = s / (float)D;
  float inv = rsqrtf(s2 / (float)D - m * m + 1e-5f);
  ushort8 ou;
  for (int t = 0; t < 8; t++) {
    int c = lane * 8 + t;
    ou[t] = f2b((v[t] - m) * inv * ldf(g, goff + c, bf) + ldf(bta, goff + c, bf));
  }
  *(ushort8*)(out + (size_t)row * D + lane * 8) = ou;
}

// ---------------------------------------------------------------------------
// k_loss: recon head + masked MSE. Block per (b,p).
// ---------------------------------------------------------------------------
__global__ void k_loss(const unsigned short* tokf, const void* Wp,
                       const void* bp, const float* patches,
                       const float* stdev, const int* mask_i,
                       const int* flags, float* scal) {
  int bpI = blockIdx.x; int b = bpI >> 6, p = bpI & 63;
  int bf = flags[0];
  int tid = threadIdx.x;
  float local = 0.f;
  for (int e = tid * 4; e < tid * 4 + 4; e++) {
    int v = e >> 4, t = e & 15;
    int tokidx = b * L + p * 32 + v;
    if (mask_i[tokidx]) {
      float r = ldf(bp, t, bf);
      for (int d = 0; d < D; d++)
        r += b2f(tokf[(size_t)tokidx * D + d]) * ldf(Wp, d * PL + t, bf);
      float diff = r - patches[tokidx * PL + t];
      float sc = stdev[b * NV + v];
      local += sc * sc * diff * diff;
    }
  }
  __shared__ float red[128];
  red[tid] = local;
  __syncthreads();
  for (int s = 64; s; s >>= 1) {
    if (tid < s) red[tid] += red[tid + s];
    __syncthreads();
  }
  if (tid == 0) atomicAdd(&scal[0], red[0]);
}

__global__ void k_final(const float* scal, const int* flags, unsigned* out) {
  float denom = (float)flags[1] * (float)PL;
  if (denom == 0.f) denom = 1.f;
  float loss = scal[0] / denom;
  unsigned fb = __float_as_uint(loss);
  unsigned u = (fb + 0x7FFFu + ((fb >> 16) & 1u)) >> 16;
  out[0] = (u << 16) | u;
}

}  // namespace

extern "C" void kernel_launch(void* const* d_in, const int* in_sizes, int n_in,
                              void* d_out, int out_size, void* d_ws,
                              size_t ws_size, hipStream_t stream) {
  const void* x_enc = d_in[0];
  const void* maskp = d_in[1];
  const void* We = d_in[2];  const void* be_ = d_in[3];
  const void* Wq = d_in[4];  const void* bq = d_in[5];
  const void* Wk = d_in[6];  const void* bk = d_in[7];
  const void* Wv = d_in[8];  const void* bv = d_in[9];
  const void* Wo = d_in[10]; const void* bo_ = d_in[11];
  const void* W1 = d_in[12]; const void* b1 = d_in[13];
  const void* W2 = d_in[14]; const void* b2 = d_in[15];
  const void* g1 = d_in[16]; const void* be1 = d_in[17];
  const void* g2 = d_in[18]; const void* be2 = d_in[19];
  const void* gf = d_in[20]; const void* bff = d_in[21];
  const void* Wp = d_in[22]; const void* bp = d_in[23];

  constexpr size_t MB = 1u << 20;
  char* w = (char*)d_ws;
  int*   mask_i  = (int*)w;                        // 32 KB
  int*   flags   = (int*)(w + 32768);
  float* scal    = (float*)(w + 32896);
  float* means   = (float*)(w + 33024);
  float* stdev   = (float*)(w + 33600);
  float* biasf   = (float*)(w + 36864);            // 73728 B
  float* patches = (float*)(w + 131072);           // 512 KB
  unsigned short* qkvT = (unsigned short*)(w + 1 * MB);   // 6 MB
  unsigned short* WoT  = (unsigned short*)(w + 7 * MB);   // 2 MB
  unsigned short* W1T  = (unsigned short*)(w + 9 * MB);   // 8 MB
  unsigned short* W2T  = (unsigned short*)(w + 17 * MB);  // 8 MB
  unsigned short* tok  = (unsigned short*)(w + 25 * MB);  // 8 MB
  unsigned short* tmp  = (unsigned short*)(w + 33 * MB);  // 8 MB
  unsigned short* ob   = (unsigned short*)(w + 41 * MB);  // 8 MB
  unsigned short* qkv  = (unsigned short*)(w + 49 * MB);  // 24 MB -> ends 73MB
  unsigned short* hidden = ob;                            // 32 MB alias (o+qkv)

  k_setup<<<1, 256, 0, stream>>>(gf, maskp, mask_i, flags, scal);
  k_stats<<<Bn * NV, 64, 0, stream>>>(x_enc, flags, means, stdev);
  k_bias<<<72, 256, 0, stream>>>(bq, bk, bv, bo_, b1, b2, flags, biasf);
  // weight transposes -> bf16 [N][K]
  k_transpose<<<dim3(16, 16, 4), 256, 0, stream>>>(Wq, qkvT, 512, 512, 262144,
                                                   786432, 0, flags);
  k_transpose<<<dim3(16, 16, 4), 256, 0, stream>>>(Wk, qkvT, 512, 512, 262144,
                                                   786432, 262144, flags);
  k_transpose<<<dim3(16, 16, 4), 256, 0, stream>>>(Wv, qkvT, 512, 512, 262144,
                                                   786432, 524288, flags);
  k_transpose<<<dim3(16, 16, 4), 256, 0, stream>>>(Wo, WoT, 512, 512, 262144,
                                                   262144, 0, flags);
  k_transpose<<<dim3(64, 16, 4), 256, 0, stream>>>(W1, W1T, 512, 2048, 1048576,
                                                   1048576, 0, flags);
  k_transpose<<<dim3(16, 64, 4), 256, 0, stream>>>(W2, W2T, 2048, 512, 1048576,
                                                   1048576, 0, flags);
  k_embed<<<M, 128, 0, stream>>>(x_enc, We, be_, flags, mask_i, means, stdev,
                                 patches, tok);
  for (int l = 0; l < 4; l++) {
    k_gemm<128, 64><<<dim3(12, 64), 256, 0, stream>>>(
        tok, qkvT + (size_t)l * 786432, biasf + l * 1536, nullptr, qkv, 1536,
        512, 0);
    k_attn<<<dim3(P, H, Bn), 256, 0, stream>>>(qkv, ob);
    k_gemm<64, 32><<<dim3(4, 128), 256, 0, stream>>>(
        ob, WoT + (size_t)l * 262144, biasf + 6144 + l * 512, tok, tmp, 512,
        512, 0);
    k_ln<<<M / 4, 256, 0, stream>>>(tmp, g1, be1, tok, flags, l * 512);
    k_gemm<128, 64><<<dim3(16, 64), 256, 0, stream>>>(
        tok, W1T + (size_t)l * 1048576, biasf + 8192 + l * 2048, nullptr,
        hidden, 2048, 512, 1);
    k_gemm<64, 32><<<dim3(4, 128), 256, 0, stream>>>(
        hidden, W2T + (size_t)l * 1048576, biasf + 16384 + l * 512, tok, tmp,
        512, 2048, 0);
    k_ln<<<M / 4, 256, 0, stream>>>(tmp, g2, be2, tok, flags, l * 512);
  }
  k_ln<<<M / 4, 256, 0, stream>>>(tok, gf, bff, tmp, flags, 0);
  k_loss<<<Bn * P, 128, 0, stream>>>(tmp, Wp, bp, patches, stdev, mask_i,
                                     flags, scal);
  k_final<<<1, 1, 0, stream>>>(scal, flags, (unsigned*)d_out);
}

// Round 3
// 1189.826 us; speedup vs baseline: 7.4058x; 1.1029x over previous
//
#include <hip/hip_runtime.h>
#include <hip/hip_bf16.h>

#define DEV __device__ __forceinline__

namespace {

constexpr int Bn  = 4, SEQ = 1024, NV = 32, PL = 16, D = 512, H = 8, DFF = 2048;
constexpr int P   = SEQ / PL;    // 64 patches
constexpr int L   = P * NV;      // 2048 tokens per batch
constexpr int M   = Bn * L;      // 8192 total token rows
constexpr int WIN = 4;

using short8  = __attribute__((ext_vector_type(8))) short;
using ushort8 = __attribute__((ext_vector_type(8))) unsigned short;
using float4v = __attribute__((ext_vector_type(4))) float;

DEV float b2f(unsigned short u) { return __uint_as_float(((unsigned)u) << 16); }
DEV unsigned short f2b(float f) {
  unsigned fb = __float_as_uint(f);
  return (unsigned short)((fb + 0x7FFFu + ((fb >> 16) & 1u)) >> 16);
}
// flag-dispatched float load from an input tensor: bf=1 -> bf16, 0 -> fp32
DEV float ldf(const void* p, size_t idx, int bf) {
  if (bf) return b2f(((const unsigned short*)p)[idx]);
  return ((const float*)p)[idx];
}
// async global->LDS 16B: lds dest = wave-uniform base + lane*16
DEV void gll16(const void* gp, void* lp) {
  __builtin_amdgcn_global_load_lds(
      (const __attribute__((address_space(1))) void*)gp,
      (__attribute__((address_space(3))) void*)lp, 16, 0, 0);
}

// ---------------------------------------------------------------------------
// k_setup: detect float dtype + mask format, canonicalize mask, count masked.
// ---------------------------------------------------------------------------
__global__ void k_setup(const void* gf, const void* mask_raw, int* mask_i,
                        int* flags, float* scal) {
  __shared__ int s_gt1, s_oth, s_cnt;
  int tid = threadIdx.x;
  if (tid == 0) { s_gt1 = 0; s_oth = 0; s_cnt = 0; }
  __syncthreads();
  const unsigned* mw = (const unsigned*)mask_raw;
  int gt1 = 0, oth = 0;
  for (int i = tid; i < 2048; i += 256) {
    unsigned w = mw[i];
    if (w > 1u) { gt1 = 1; if (w != 0x3F800000u) oth = 1; }
  }
  if (gt1) atomicOr(&s_gt1, 1);
  if (oth) atomicOr(&s_oth, 1);
  __syncthreads();
  int fmt = (!s_gt1) ? 0 : (!s_oth ? 1 : 2);  // 0=int32, 1=f32, 2=bytes
  int cnt = 0;
  for (int i = tid; i < Bn * P * NV; i += 256) {
    int m;
    if (fmt == 0)      m = ((const int*)mask_raw)[i] != 0;
    else if (fmt == 1) m = ((const float*)mask_raw)[i] != 0.0f;
    else               m = ((const unsigned char*)mask_raw)[i] != 0;
    mask_i[i] = m; cnt += m;
  }
  atomicAdd(&s_cnt, cnt);
  __syncthreads();
  if (tid == 0) {
    unsigned w = *(const unsigned*)gf;
    flags[0] = ((w & 0xFFFFu) == 0x3F80u) ? 1 : 0;
    flags[1] = s_cnt;
    scal[0] = 0.f;
  }
}

// ---------------------------------------------------------------------------
// k_prep: blocks 0..31 -> per-(b,v) stats; blocks 32.. -> gather biases,
// final-LN weights (fp32), b_proj (fp32), and WpT (bf16 [t][d]).
// biasf: qkvb l*1536 | 6144+obias l*512 | 8192+b1 l*2048 | 16384+b2 l*512
// lnw:   gf[0:512] | bff[512:1024] | bp[1024:1040]
// ---------------------------------------------------------------------------
__global__ void k_prep(const void* x, const void* bq, const void* bk,
                       const void* bv, const void* bo, const void* b1,
                       const void* b2, const void* gf, const void* bff,
                       const void* Wp, const void* bp, const int* flags,
                       float* means, float* stdev, float* biasf, float* lnw,
                       unsigned short* WpT) {
  int bf = flags[0];
  int tid = threadIdx.x;
  if (blockIdx.x < 32) {
    int bv_ = blockIdx.x * 4 + (tid >> 6);
    int b = bv_ >> 5, v = bv_ & 31;
    int lane = tid & 63;
    float s = 0.f, s2 = 0.f;
    for (int t = lane; t < SEQ; t += 64) {
      float val = ldf(x, (size_t)b * SEQ * NV + (size_t)t * NV + v, bf);
      s += val; s2 += val * val;
    }
    for (int off = 32; off; off >>= 1) {
      s += __shfl_xor(s, off); s2 += __shfl_xor(s2, off);
    }
    if (lane == 0) {
      float m = s / (float)SEQ;
      means[bv_] = m;
      stdev[bv_] = sqrtf(s2 / (float)SEQ - m * m + 1e-5f);
    }
    return;
  }
  int i = (blockIdx.x - 32) * 256 + tid;
  if (i < 18432) {
    int l = i / 4608, r = i % 4608;
    if (r < 1536) {
      float v = (r < 512) ? ldf(bq, l * 512 + r, bf)
              : (r < 1024) ? ldf(bk, l * 512 + r - 512, bf)
                           : ldf(bv, l * 512 + r - 1024, bf);
      biasf[l * 1536 + r] = v;
    } else if (r < 2048) {
      biasf[6144 + l * 512 + (r - 1536)] = ldf(bo, l * 512 + r - 1536, bf);
    } else if (r < 4096) {
      biasf[8192 + l * 2048 + (r - 2048)] = ldf(b1, l * 2048 + r - 2048, bf);
    } else {
      biasf[16384 + l * 512 + (r - 4096)] = ldf(b2, l * 512 + r - 4096, bf);
    }
  } else if (i < 19456) {
    int j = i - 18432;
    lnw[j] = (j < 512) ? ldf(gf, j, bf) : ldf(bff, j - 512, bf);
  } else if (i < 19472) {
    lnw[1024 + (i - 19456)] = ldf(bp, i - 19456, bf);
  } else if (i < 27664) {
    int j = i - 19472; int t = j >> 9, d = j & 511;
    WpT[j] = f2b(ldf(Wp, d * 16 + t, bf));
  }
}

// ---------------------------------------------------------------------------
// k_transpose_all: all 6 weight transposes in one dispatch.
// dst[l][n][k] (bf16) = src[l][k][n]. 32x32 LDS tile per block.
// ---------------------------------------------------------------------------
__global__ void k_transpose_all(const void* Wq, const void* Wk, const void* Wv,
                                const void* Wo, const void* W1, const void* W2,
                                unsigned short* qkvT, unsigned short* WoT,
                                unsigned short* W1T, unsigned short* W2T,
                                const int* flags) {
  int bf = flags[0];
  int id = blockIdx.x;
  const void* src; unsigned short* dst;
  int Kd, Nd, l, n0, k0, dstOff = 0;
  size_t srcLS, dstLS;
  if (id < 4096) {
    int tensor = id >> 10, rem = id & 1023;
    l = rem >> 8; int t = rem & 255;
    n0 = (t & 15) * 32; k0 = (t >> 4) * 32;
    Kd = 512; Nd = 512; srcLS = 262144;
    if (tensor == 0)      { src = Wq; dst = qkvT; dstLS = 786432; dstOff = 0; }
    else if (tensor == 1) { src = Wk; dst = qkvT; dstLS = 786432; dstOff = 262144; }
    else if (tensor == 2) { src = Wv; dst = qkvT; dstLS = 786432; dstOff = 524288; }
    else                  { src = Wo; dst = WoT;  dstLS = 262144; }
  } else if (id < 8192) {
    int rem = id - 4096; l = rem >> 10; int t = rem & 1023;
    n0 = (t & 63) * 32; k0 = (t >> 6) * 32;
    Kd = 512; Nd = 2048; srcLS = 1048576; src = W1; dst = W1T; dstLS = 1048576;
  } else {
    int rem = id - 8192; l = rem >> 10; int t = rem & 1023;
    n0 = (t & 15) * 32; k0 = (t >> 4) * 32;
    Kd = 2048; Nd = 512; srcLS = 1048576; src = W2; dst = W2T; dstLS = 1048576;
  }
  int tx = threadIdx.x & 31, ty = threadIdx.x >> 5;
  __shared__ float tile[32][33];
  for (int rr = ty; rr < 32; rr += 8)
    tile[rr][tx] =
        ldf(src, (size_t)l * srcLS + (size_t)(k0 + rr) * Nd + n0 + tx, bf);
  __syncthreads();
  for (int rr = ty; rr < 32; rr += 8)
    dst[(size_t)l * dstLS + dstOff + (size_t)(n0 + rr) * Kd + k0 + tx] =
        f2b(tile[tx][rr]);
}

// ---------------------------------------------------------------------------
// k_embed: patchify + instance-normalize, write patches (fp32) and embedded
// tokens (bf16), zeroing masked tokens. One block (128 thr) per token.
// ---------------------------------------------------------------------------
__global__ void k_embed(const void* x, const void* We, const void* be,
                        const int* flags, const int* mask_i,
                        const float* means, const float* stdev,
                        float* patches, unsigned short* tok) {
  int idx = blockIdx.x;
  int b = idx >> 11, pv = idx & 2047, p = pv >> 5, v = pv & 31;
  int bf = flags[0];
  __shared__ float pvs[PL];
  int tid = threadIdx.x;
  float m = means[b * NV + v], sd = stdev[b * NV + v];
  if (tid < PL) {
    float val =
        (ldf(x, (size_t)b * SEQ * NV + (size_t)(p * PL + tid) * NV + v, bf) -
         m) / sd;
    pvs[tid] = val;
    patches[(size_t)idx * PL + tid] = val;
  }
  __syncthreads();
  int masked = mask_i[idx];
  for (int d = tid; d < D; d += 128) {
    float acc = ldf(be, d, bf);
    for (int t = 0; t < PL; t++) acc += pvs[t] * ldf(We, t * D + d, bf);
    tok[(size_t)idx * D + d] = masked ? f2b(0.f) : f2b(acc);
  }
}

// ---------------------------------------------------------------------------
// k_gemm<BM,WN>: C[bm..][bn..] = act(A @ W^T' + bias [+resid]) in bf16.
// A: [M][Kk] bf16 row-major; W: pre-transposed [Nn][Kk] bf16 row-major.
// 256 thr = 4 waves; tile BM x 128; wave computes 64 x WN via 16x16x32 MFMA.
// ---------------------------------------------------------------------------
template <int BM, int WN>
__global__ __launch_bounds__(256) void k_gemm(
    const unsigned short* __restrict__ A, const unsigned short* __restrict__ W,
    const float* __restrict__ bias, const unsigned short* __restrict__ resid,
    unsigned short* __restrict__ C, int Nn, int Kk, int act) {
  constexpr int FI = 4, FJ = WN / 16, NWN = 128 / WN;
  __shared__ __align__(16) char As[BM * 64];    // BM x 32 bf16
  __shared__ __align__(16) char Bs[128 * 64];   // 128 x 32 bf16
  int tid = threadIdx.x, lane = tid & 63, w = tid >> 6;
  int lane15 = lane & 15, q = lane >> 4;
  int wm = w / NWN, wn = w % NWN;
  int bm = blockIdx.y * BM, bn = blockIdx.x * 128;
  float4v acc[FI][FJ];
  for (int i = 0; i < FI; i++)
    for (int j = 0; j < FJ; j++) acc[i][j] = 0;
  for (int k0 = 0; k0 < Kk; k0 += 32) {
    if (k0) __syncthreads();
    for (int r = 0; r < BM / 64; r++) {
      int cc = r * 256 + w * 64 + lane;
      int row = cc >> 2, kc = cc & 3;
      gll16(A + (size_t)(bm + row) * Kk + k0 + kc * 8,
            As + (r * 256 + w * 64) * 16);
    }
    for (int r = 0; r < 2; r++) {
      int cc = r * 256 + w * 64 + lane;
      int row = cc >> 2, kc = cc & 3;
      gll16(W + (size_t)(bn + row) * Kk + k0 + kc * 8,
            Bs + (r * 256 + w * 64) * 16);
    }
    __syncthreads();
    short8 a[FI], b[FJ];
    for (int i = 0; i < FI; i++)
      a[i] = *(const short8*)(As + (wm * 64 + i * 16 + lane15) * 64 + q * 16);
    for (int j = 0; j < FJ; j++)
      b[j] = *(const short8*)(Bs + (wn * WN + j * 16 + lane15) * 64 + q * 16);
    for (int i = 0; i < FI; i++)
      for (int j = 0; j < FJ; j++)
        acc[i][j] = __builtin_amdgcn_mfma_f32_16x16x32_bf16(a[i], b[j],
                                                            acc[i][j], 0, 0, 0);
  }
  for (int i = 0; i < FI; i++) {
    int row = bm + wm * 64 + i * 16 + q * 4;
    for (int j = 0; j < FJ; j++) {
      int col = bn + wn * WN + j * 16 + lane15;
      float bv = bias[col];
      for (int r = 0; r < 4; r++) {
        float cv = acc[i][j][r] + bv;
        size_t off = (size_t)(row + r) * Nn + col;
        if (resid) cv += b2f(resid[off]);
        if (act) cv = 0.5f * cv * (1.f + erff(cv * 0.70710678f));
        C[off] = f2b(cv);
      }
    }
  }
}

// ---------------------------------------------------------------------------
// k_attn: banded MFMA attention. Block per (p,h,b), 4 waves.
// qkv: [M][1536] bf16 (q|k|v). o: [M][512] bf16.
// LDS plan (63744 B static):
//   [0,4608)      Qs 32x72 bf16      (phase A)   -> Ps 32x296 bf16 (phase B/C)
//   [4608,25344)  Ks 144x72 bf16     (phase A, two window halves)
//   [25344,63744) Ss 32x300 fp32     (scores)    -> Vt 64x296 bf16 (phase C)
// ---------------------------------------------------------------------------
__global__ __launch_bounds__(256) void k_attn(const unsigned short* __restrict__ qkv,
                                              unsigned short* __restrict__ o) {
  constexpr int QS = 0, KS = 4608, PS = 0, SS = 25344, VT = 25344;
  __shared__ __align__(16) char sm[63744];
  int p = blockIdx.x, h = blockIdx.y, b = blockIdx.z;
  int tid = threadIdx.x, lane = tid & 63, w = tid >> 6;
  int lane15 = lane & 15, q = lane >> 4;
  int p0 = max(0, p - WIN), p1 = min(P - 1, p + WIN);
  int nk = (p1 - p0 + 1) * 32;              // multiple of 32, in [160,288]
  size_t base = (size_t)b * L;
  size_t qrow0 = (base + p * 32) * 1536 + (size_t)h * 64;
  size_t krow0 = (base + p0 * 32) * 1536 + 512 + (size_t)h * 64;
  size_t vrow0 = (base + p0 * 32) * 1536 + 1024 + (size_t)h * 64;
  int mtile = w & 1;
  short8 aq[2];
  // ---- phase A: S = Q K^T (two halves of the 288-key window) ----
  for (int half = 0; half < 2; half++) {
    if (half) __syncthreads();
    for (int e = tid; e < 144 * 8; e += 256) {
      int jr = e >> 3, sub = e & 7;
      if (half * 144 + jr < nk) {
        ushort8 t = *(const ushort8*)(qkv + krow0 +
                                      (size_t)(half * 144 + jr) * 1536 + sub * 8);
        *(ushort8*)(sm + KS + jr * 144 + sub * 16) = t;
      }
    }
    if (half == 0) {
      int rr = tid >> 3, sub = tid & 7;
      ushort8 t = *(const ushort8*)(qkv + qrow0 + (size_t)rr * 1536 + sub * 8);
      *(ushort8*)(sm + QS + rr * 144 + sub * 16) = t;
    }
    __syncthreads();
    if (half == 0) {
      aq[0] = *(const short8*)(sm + QS + (mtile * 16 + lane15) * 144 + q * 16);
      aq[1] = *(const short8*)(sm + QS + (mtile * 16 + lane15) * 144 + 64 + q * 16);
    }
    for (int nt = (w >> 1); nt < 9; nt += 2) {
      if (half * 144 + nt * 16 >= nk) break;
      short8 b0 = *(const short8*)(sm + KS + (nt * 16 + lane15) * 144 + q * 16);
      short8 b1 = *(const short8*)(sm + KS + (nt * 16 + lane15) * 144 + 64 + q * 16);
      float4v s4 = 0;
      s4 = __builtin_amdgcn_mfma_f32_16x16x32_bf16(aq[0], b0, s4, 0, 0, 0);
      s4 = __builtin_amdgcn_mfma_f32_16x16x32_bf16(aq[1], b1, s4, 0, 0, 0);
      float* ss = (float*)(sm + SS);
      for (int r = 0; r < 4; r++)
        ss[(mtile * 16 + q * 4 + r) * 300 + half * 144 + nt * 16 + lane15] = s4[r];
    }
  }
  __syncthreads();
  // ---- phase B: softmax (8 threads per row), write P bf16 into PS ----
  {
    float* ss = (float*)(sm + SS);
    unsigned short* ps = (unsigned short*)(sm + PS);
    int row = tid >> 3, c = tid & 7;
    float mx = -3e38f;
    for (int j = c; j < nk; j += 8) mx = fmaxf(mx, ss[row * 300 + j] * 0.125f);
    for (int off = 1; off < 8; off <<= 1) mx = fmaxf(mx, __shfl_xor(mx, off));
    float sum = 0.f;
    for (int j = c; j < nk; j += 8) {
      float e = __expf(ss[row * 300 + j] * 0.125f - mx);
      ss[row * 300 + j] = e; sum += e;
    }
    for (int off = 1; off < 8; off <<= 1) sum += __shfl_xor(sum, off);
    float inv = 1.f / sum;
    for (int j = c; j < nk; j += 8)
      ps[row * 296 + j] = f2b(ss[row * 300 + j] * inv);
  }
  __syncthreads();
  // ---- phase C: load V^T over Ss (vectorized global side), O = P V ----
  {
    unsigned short* vt = (unsigned short*)(sm + VT);
    for (int e = tid; e < nk * 8; e += 256) {
      int kl = e >> 3, sub = e & 7;
      ushort8 v8 = *(const ushort8*)(qkv + vrow0 + (size_t)kl * 1536 + sub * 8);
      for (int j = 0; j < 8; j++) vt[(sub * 8 + j) * 296 + kl] = v8[j];
    }
  }
  __syncthreads();
  int ntb = (w >> 1) * 2;
  float4v oa[2]; oa[0] = 0; oa[1] = 0;
  for (int kt = 0; kt < (nk >> 5); kt++) {
    short8 ap = *(const short8*)(sm + PS + (mtile * 16 + lane15) * 592 +
                                 kt * 64 + q * 16);
    for (int jj = 0; jj < 2; jj++) {
      short8 bv = *(const short8*)(sm + VT + ((ntb + jj) * 16 + lane15) * 592 +
                                   kt * 64 + q * 16);
      oa[jj] = __builtin_amdgcn_mfma_f32_16x16x32_bf16(ap, bv, oa[jj], 0, 0, 0);
    }
  }
  for (int jj = 0; jj < 2; jj++)
    for (int r = 0; r < 4; r++)
      o[(base + p * 32 + mtile * 16 + q * 4 + r) * 512 + h * 64 +
        (ntb + jj) * 16 + lane15] = f2b(oa[jj][r]);
}

// ---------------------------------------------------------------------------
// k_ln: layernorm over D=512 per token, bf16 in/out. 4 rows per block.
// ---------------------------------------------------------------------------
__global__ void k_ln(const unsigned short* __restrict__ x, const void* g,
                     const void* bta, unsigned short* __restrict__ out,
                     const int* flags, int goff) {
  int bf = flags[0];
  int row = blockIdx.x * 4 + (threadIdx.x >> 6);
  int lane = threadIdx.x & 63;
  ushort8 u = *(const ushort8*)(x + (size_t)row * D + lane * 8);
  float v[8]; float s = 0.f, s2 = 0.f;
  for (int t = 0; t < 8; t++) {
    v[t] = b2f(u[t]); s += v[t]; s2 += v[t] * v[t];
  }
  for (int off = 32; off; off >>= 1) {
    s += __shfl_xor(s, off); s2 += __shfl_xor(s2, off);
  }
  float m = s / (float)D;
  float inv = rsqrtf(s2 / (float)D - m * m + 1e-5f);
  ushort8 ou;
  for (int t = 0; t < 8; t++) {
    int c = lane * 8 + t;
    ou[t] = f2b((v[t] - m) * inv * ldf(g, goff + c, bf) + ldf(bta, goff + c, bf));
  }
  *(ushort8*)(out + (size_t)row * D + lane * 8) = ou;
}

// ---------------------------------------------------------------------------
// k_lnloss: fused final LN + recon head (MFMA) + masked MSE.
// Block per (b,p): 32 tokens. 128 thr = 2 waves; wave w handles m-tile w.
// ---------------------------------------------------------------------------
__global__ __launch_bounds__(128) void k_lnloss(
    const unsigned short* __restrict__ tok, const float* __restrict__ lnw,
    const unsigned short* __restrict__ WpT, const float* __restrict__ patches,
    const float* __restrict__ stdev, const int* __restrict__ mask_i,
    float* scal) {
  constexpr int RS = 520;  // padded LDS row stride (elements)
  __shared__ __align__(16) unsigned short As[32 * RS];
  __shared__ __align__(16) unsigned short Bs[16 * RS];
  int bpI = blockIdx.x; int b = bpI >> 6, p = bpI & 63;
  int tid = threadIdx.x;
  int row = tid >> 2, cg = tid & 3;   // 4 threads per token row
  size_t tokbase = (size_t)(b * L + p * 32);
  // pass 1: stats
  float s = 0.f, s2 = 0.f;
  for (int i = 0; i < 16; i++) {
    int c = cg + i * 4;
    ushort8 u = *(const ushort8*)(tok + (tokbase + row) * D + c * 8);
    for (int t = 0; t < 8; t++) { float v = b2f(u[t]); s += v; s2 += v * v; }
  }
  s += __shfl_xor(s, 1); s += __shfl_xor(s, 2);
  s2 += __shfl_xor(s2, 1); s2 += __shfl_xor(s2, 2);
  float m = s / (float)D;
  float inv = rsqrtf(s2 / (float)D - m * m + 1e-5f);
  // pass 2: normalize into LDS (re-read from L1/L2-hot global)
  for (int i = 0; i < 16; i++) {
    int c = cg + i * 4;
    ushort8 u = *(const ushort8*)(tok + (tokbase + row) * D + c * 8);
    ushort8 o;
    for (int t = 0; t < 8; t++) {
      int col = c * 8 + t;
      o[t] = f2b((b2f(u[t]) - m) * inv * lnw[col] + lnw[512 + col]);
    }
    *(ushort8*)(As + row * RS + c * 8) = o;
  }
  // stage WpT
  for (int e = tid; e < 16 * 64; e += 128) {
    int r = e >> 6, c = e & 63;
    *(ushort8*)(Bs + r * RS + c * 8) = *(const ushort8*)(WpT + r * 512 + c * 8);
  }
  __syncthreads();
  int w = tid >> 6, lane = tid & 63, lane15 = lane & 15, q = lane >> 4;
  float4v acc = 0;
  for (int kt = 0; kt < 16; kt++) {
    short8 a = *(const short8*)(As + (w * 16 + lane15) * RS + kt * 32 + q * 8);
    short8 bfr = *(const short8*)(Bs + lane15 * RS + kt * 32 + q * 8);
    acc = __builtin_amdgcn_mfma_f32_16x16x32_bf16(a, bfr, acc, 0, 0, 0);
  }
  float local = 0.f;
  int t = lane15;
  for (int r = 0; r < 4; r++) {
    int v = w * 16 + q * 4 + r;
    int tokidx = b * 2048 + p * 32 + v;
    if (mask_i[tokidx]) {
      float recon = acc[r] + lnw[1024 + t];
      float diff = recon - patches[(size_t)tokidx * 16 + t];
      float sc = stdev[b * 32 + v];
      local += sc * sc * diff * diff;
    }
  }
  for (int off = 32; off; off >>= 1) local += __shfl_xor(local, off);
  if (lane == 0) atomicAdd(&scal[0], local);
}

__global__ void k_final(const float* scal, const int* flags, unsigned* out) {
  float denom = (float)flags[1] * (float)PL;
  if (denom == 0.f) denom = 1.f;
  float loss = scal[0] / denom;
  unsigned fb = __float_as_uint(loss);
  unsigned u = (fb + 0x7FFFu + ((fb >> 16) & 1u)) >> 16;
  out[0] = (u << 16) | u;
}

}  // namespace

extern "C" void kernel_launch(void* const* d_in, const int* in_sizes, int n_in,
                              void* d_out, int out_size, void* d_ws,
                              size_t ws_size, hipStream_t stream) {
  const void* x_enc = d_in[0];
  const void* maskp = d_in[1];
  const void* We = d_in[2];  const void* be_ = d_in[3];
  const void* Wq = d_in[4];  const void* bq = d_in[5];
  const void* Wk = d_in[6];  const void* bk = d_in[7];
  const void* Wv = d_in[8];  const void* bv = d_in[9];
  const void* Wo = d_in[10]; const void* bo_ = d_in[11];
  const void* W1 = d_in[12]; const void* b1 = d_in[13];
  const void* W2 = d_in[14]; const void* b2 = d_in[15];
  const void* g1 = d_in[16]; const void* be1 = d_in[17];
  const void* g2 = d_in[18]; const void* be2 = d_in[19];
  const void* gf = d_in[20]; const void* bff = d_in[21];
  const void* Wp = d_in[22]; const void* bp = d_in[23];

  constexpr size_t MB = 1u << 20;
  char* w = (char*)d_ws;
  int*   mask_i  = (int*)w;                        // 32 KB
  int*   flags   = (int*)(w + 32768);
  float* scal    = (float*)(w + 32896);
  float* means   = (float*)(w + 33024);
  float* stdev   = (float*)(w + 33600);
  float* biasf   = (float*)(w + 36864);            // 73728 B -> ends 110592
  float* lnw     = (float*)(w + 114688);           // 4160 B
  float* patches = (float*)(w + 131072);           // 512 KB -> ends 655360
  unsigned short* WpT = (unsigned short*)(w + 655360);    // 16 KB
  unsigned short* qkvT = (unsigned short*)(w + 1 * MB);   // 6 MB
  unsigned short* WoT  = (unsigned short*)(w + 7 * MB);   // 2 MB
  unsigned short* W1T  = (unsigned short*)(w + 9 * MB);   // 8 MB
  unsigned short* W2T  = (unsigned short*)(w + 17 * MB);  // 8 MB
  unsigned short* tok  = (unsigned short*)(w + 25 * MB);  // 8 MB
  unsigned short* tmp  = (unsigned short*)(w + 33 * MB);  // 8 MB
  unsigned short* ob   = (unsigned short*)(w + 41 * MB);  // 8 MB
  unsigned short* qkv  = (unsigned short*)(w + 49 * MB);  // 24 MB -> ends 73MB
  unsigned short* hidden = ob;                            // 32 MB alias (o+qkv)

  k_setup<<<1, 256, 0, stream>>>(gf, maskp, mask_i, flags, scal);
  k_prep<<<141, 256, 0, stream>>>(x_enc, bq, bk, bv, bo_, b1, b2, gf, bff, Wp,
                                  bp, flags, means, stdev, biasf, lnw, WpT);
  k_transpose_all<<<12288, 256, 0, stream>>>(Wq, Wk, Wv, Wo, W1, W2, qkvT, WoT,
                                             W1T, W2T, flags);
  k_embed<<<M, 128, 0, stream>>>(x_enc, We, be_, flags, mask_i, means, stdev,
                                 patches, tok);
  for (int l = 0; l < 4; l++) {
    k_gemm<128, 64><<<dim3(12, 64), 256, 0, stream>>>(
        tok, qkvT + (size_t)l * 786432, biasf + l * 1536, nullptr, qkv, 1536,
        512, 0);
    k_attn<<<dim3(P, H, Bn), 256, 0, stream>>>(qkv, ob);
    k_gemm<128, 64><<<dim3(4, 64), 256, 0, stream>>>(
        ob, WoT + (size_t)l * 262144, biasf + 6144 + l * 512, tok, tmp, 512,
        512, 0);
    k_ln<<<M / 4, 256, 0, stream>>>(tmp, g1, be1, tok, flags, l * 512);
    k_gemm<128, 64><<<dim3(16, 64), 256, 0, stream>>>(
        tok, W1T + (size_t)l * 1048576, biasf + 8192 + l * 2048, nullptr,
        hidden, 2048, 512, 1);
    k_gemm<128, 64><<<dim3(4, 64), 256, 0, stream>>>(
        hidden, W2T + (size_t)l * 1048576, biasf + 16384 + l * 512, tok, tmp,
        512, 2048, 0);
    k_ln<<<M / 4, 256, 0, stream>>>(tmp, g2, be2, tok, flags, l * 512);
  }
  k_lnloss<<<Bn * P, 128, 0, stream>>>(tok, lnw, WpT, patches, stdev, mask_i,
                                       scal);
  k_final<<<1, 1, 0, stream>>>(scal, flags, (unsigned*)d_out);
}